// Round 4
// baseline (1369.765 us; speedup 1.0000x reference)
//
#include <hip/hip_runtime.h>
#include <hip/hip_cooperative_groups.h>

namespace cg = cooperative_groups;

typedef float  f32x2  __attribute__((ext_vector_type(2)));
typedef float  f32x4  __attribute__((ext_vector_type(4)));
typedef __bf16 bf16x8 __attribute__((ext_vector_type(8)));
typedef unsigned uint4v __attribute__((ext_vector_type(4)));

// split fp32 pair into packed bf16 hi-pair and lo-pair (3-term MFMA emulation)
static __device__ __forceinline__ void split_pair(float a, float b, unsigned& hp, unsigned& lp) {
    __bf16 ha = (__bf16)a, hb = (__bf16)b;
    hp = (unsigned)__builtin_bit_cast(unsigned short, ha) |
         ((unsigned)__builtin_bit_cast(unsigned short, hb) << 16);
    __bf16 la = (__bf16)(a - (float)ha), lb = (__bf16)(b - (float)hb);
    lp = (unsigned)__builtin_bit_cast(unsigned short, la) |
         ((unsigned)__builtin_bit_cast(unsigned short, lb) << 16);
}

static __device__ __forceinline__ void split8(f32x4 u, f32x4 v, bf16x8& h8, bf16x8& l8) {
    float f[8] = {u.x, u.y, u.z, u.w, v.x, v.y, v.z, v.w};
    #pragma unroll
    for (int t = 0; t < 8; ++t) {
        __bf16 h = (__bf16)f[t];
        h8[t] = h;
        l8[t] = (__bf16)(f[t] - (float)h);
    }
}

// ================= shared phase bodies (used by mega AND fallback kernels) =================

// aggregate x for node w -> pre-split bf16 hi/lo planes
static __device__ __forceinline__ void aggx_body(int w, int lane, const float* __restrict__ x,
                                                 const int* __restrict__ base, const int* __restrict__ cnt,
                                                 const int2* __restrict__ edge2, const float* __restrict__ dinv,
                                                 unsigned* __restrict__ AXh, unsigned* __restrict__ AXl) {
    float di = dinv[w];
    f32x2 xv = ((const f32x2*)(x + (size_t)w * 128))[lane];
    f32x2 a0 = xv * (di * di);
    f32x2 a1 = {0.f, 0.f}, a2 = {0.f, 0.f}, a3 = {0.f, 0.f};
    const int2* eb = edge2 + base[w];
    int dp = (cnt[w] + 7) & ~7;
    if (dp > 0) {
        int2 e[8];
        #pragma unroll
        for (int u = 0; u < 8; ++u) e[u] = eb[u];
        int j = 0;
        for (; j + 8 < dp; j += 8) {
            f32x2 v[8];
            #pragma unroll
            for (int u = 0; u < 8; ++u)
                v[u] = ((const f32x2*)(x + (size_t)e[u].x * 128))[lane];
            int2 en[8];
            #pragma unroll
            for (int u = 0; u < 8; ++u) en[u] = eb[j + 8 + u];
            #pragma unroll
            for (int u = 0; u < 8; ++u) {
                float nr = __int_as_float(e[u].y);
                f32x2* a = (u & 3) == 0 ? &a0 : (u & 3) == 1 ? &a1 : (u & 3) == 2 ? &a2 : &a3;
                *a += v[u] * nr;
            }
            #pragma unroll
            for (int u = 0; u < 8; ++u) e[u] = en[u];
        }
        {
            f32x2 v[8];
            #pragma unroll
            for (int u = 0; u < 8; ++u)
                v[u] = ((const f32x2*)(x + (size_t)e[u].x * 128))[lane];
            #pragma unroll
            for (int u = 0; u < 8; ++u) {
                float nr = __int_as_float(e[u].y);
                f32x2* a = (u & 3) == 0 ? &a0 : (u & 3) == 1 ? &a1 : (u & 3) == 2 ? &a2 : &a3;
                *a += v[u] * nr;
            }
        }
    }
    f32x2 o = a0 + a1 + a2 + a3;
    unsigned hp, lp;
    split_pair(o.x, o.y, hp, lp);
    __builtin_nontemporal_store(hp, AXh + (size_t)w * 64 + lane);
    __builtin_nontemporal_store(lp, AXl + (size_t)w * 64 + lane);
}

// aggregate H2 row for node w + bias + log_softmax (returns this lane's result)
static __device__ __forceinline__ float aggh2_res(int w, int lane, const float* __restrict__ H2,
                                                  const int* __restrict__ base, const int* __restrict__ cnt,
                                                  const int2* __restrict__ edge2, const float* __restrict__ dinv,
                                                  const float* __restrict__ b2) {
    float di = dinv[w];
    float a0 = H2[(size_t)w * 64 + lane] * di * di;
    float a1 = 0.f, a2 = 0.f, a3 = 0.f;
    const int2* eb = edge2 + base[w];
    int dp = (cnt[w] + 7) & ~7;
    if (dp > 0) {
        int2 e[8];
        #pragma unroll
        for (int u = 0; u < 8; ++u) e[u] = eb[u];
        int j = 0;
        for (; j + 8 < dp; j += 8) {
            float v[8];
            #pragma unroll
            for (int u = 0; u < 8; ++u) v[u] = H2[(size_t)e[u].x * 64 + lane];
            int2 en[8];
            #pragma unroll
            for (int u = 0; u < 8; ++u) en[u] = eb[j + 8 + u];
            #pragma unroll
            for (int u = 0; u < 8; ++u) {
                float nr = __int_as_float(e[u].y);
                float* a = (u & 3) == 0 ? &a0 : (u & 3) == 1 ? &a1 : (u & 3) == 2 ? &a2 : &a3;
                *a = fmaf(v[u], nr, *a);
            }
            #pragma unroll
            for (int u = 0; u < 8; ++u) e[u] = en[u];
        }
        {
            float v[8];
            #pragma unroll
            for (int u = 0; u < 8; ++u) v[u] = H2[(size_t)e[u].x * 64 + lane];
            #pragma unroll
            for (int u = 0; u < 8; ++u) {
                float nr = __int_as_float(e[u].y);
                float* a = (u & 3) == 0 ? &a0 : (u & 3) == 1 ? &a1 : (u & 3) == 2 ? &a2 : &a3;
                *a = fmaf(v[u], nr, *a);
            }
        }
    }
    float v = a0 + a1 + a2 + a3 + b2[lane];
    float m = v;
    #pragma unroll
    for (int off = 32; off > 0; off >>= 1) m = fmaxf(m, __shfl_xor(m, off, 64));
    float e = expf(v - m);
    float s = e;
    #pragma unroll
    for (int off = 32; off > 0; off >>= 1) s += __shfl_xor(s, off, 64);
    return v - m - logf(s);
}

// one 16*FI x 64 output tile of the direct-fragment MFMA GEMM (round-3 proven)
template<int K_, int FI, int CT, int APLANES, int NTIN, int NTOUT>
static __device__ __forceinline__ void gemm_tile(int gw, int lane,
                                                 const unsigned* __restrict__ Ah, const unsigned* __restrict__ Al,
                                                 const float* __restrict__ Afp,
                                                 const unsigned short* __restrict__ Bh, const unsigned short* __restrict__ Bl,
                                                 const float* __restrict__ bias, float* __restrict__ C,
                                                 int M, int N, int relu) {
    int rt = gw / CT, ct = gw % CT;
    int rows = rt * (FI * 16);
    if (rows >= M) return;
    int lg = lane >> 4, lr = lane & 15;

    size_t boff[4];
    #pragma unroll
    for (int j = 0; j < 4; ++j)
        boff[j] = (size_t)(ct * 64 + j * 16 + lr) * K_ + lg * 8;     // u16 units

    size_t aoff[FI];
    #pragma unroll
    for (int i = 0; i < FI; ++i) {
        int ar = rows + i * 16 + lr;
        if (ar >= M) ar = M - 1;
        aoff[i] = APLANES ? (size_t)ar * (K_ / 2) + lg * 4            // u32 units
                          : (size_t)ar * K_ + lg * 8;                 // f32 units
    }

    f32x4 acc[FI][4] = {};

    #pragma unroll 2
    for (int k0 = 0; k0 < K_; k0 += 32) {
        bf16x8 a_h[FI], a_l[FI];
        #pragma unroll
        for (int i = 0; i < FI; ++i) {
            if (APLANES) {
                a_h[i] = __builtin_bit_cast(bf16x8, *(const uint4v*)(Ah + aoff[i] + (k0 >> 1)));
                a_l[i] = __builtin_bit_cast(bf16x8, *(const uint4v*)(Al + aoff[i] + (k0 >> 1)));
            } else {
                const f32x4* p = (const f32x4*)(Afp + aoff[i] + k0);
                f32x4 u = NTIN ? __builtin_nontemporal_load(p)     : p[0];
                f32x4 v = NTIN ? __builtin_nontemporal_load(p + 1) : p[1];
                split8(u, v, a_h[i], a_l[i]);
            }
        }
        #pragma unroll
        for (int j = 0; j < 4; ++j) {
            bf16x8 b_h = __builtin_bit_cast(bf16x8, *(const uint4v*)(Bh + boff[j] + k0));
            bf16x8 b_l = __builtin_bit_cast(bf16x8, *(const uint4v*)(Bl + boff[j] + k0));
            #pragma unroll
            for (int i = 0; i < FI; ++i) {
                acc[i][j] = __builtin_amdgcn_mfma_f32_16x16x32_bf16(a_h[i], b_h, acc[i][j], 0, 0, 0);
                acc[i][j] = __builtin_amdgcn_mfma_f32_16x16x32_bf16(a_h[i], b_l, acc[i][j], 0, 0, 0);
                acc[i][j] = __builtin_amdgcn_mfma_f32_16x16x32_bf16(a_l[i], b_h, acc[i][j], 0, 0, 0);
            }
        }
    }

    #pragma unroll
    for (int j = 0; j < 4; ++j) {
        int col = ct * 64 + j * 16 + lr;
        float bv = bias ? bias[col] : 0.f;
        #pragma unroll
        for (int i = 0; i < FI; ++i)
            #pragma unroll
            for (int rg = 0; rg < 4; ++rg) {
                int gr = rows + i * 16 + lg * 4 + rg;
                if (gr < M) {
                    float o = acc[i][j][rg] + bv;
                    if (relu) o = fmaxf(o, 0.f);
                    if (NTOUT) __builtin_nontemporal_store(o, C + (size_t)gr * N + col);
                    else       C[(size_t)gr * N + col] = o;
                }
            }
    }
}

// ================= THE mega-kernel: whole pipeline, 7 grid syncs, 1 dispatch =================
__global__ __launch_bounds__(256, 4) void mega(const float* __restrict__ x,
                                               const float* __restrict__ W1, const float* __restrict__ W2,
                                               const float* __restrict__ b1, const float* __restrict__ b2,
                                               const int* __restrict__ ei,
                                               float* __restrict__ dinv, int* __restrict__ cnt,
                                               int* __restrict__ base, int* __restrict__ fill,
                                               int* __restrict__ total, int2* __restrict__ edge2,
                                               unsigned short* __restrict__ w1h, unsigned short* __restrict__ w1l,
                                               unsigned short* __restrict__ w2h, unsigned short* __restrict__ w2l,
                                               unsigned* __restrict__ AXh, unsigned* __restrict__ AXl,
                                               float* __restrict__ H1, float* __restrict__ H2,
                                               float* __restrict__ out, int n, int E, int copies) {
    cg::grid_group grid = cg::this_grid();
    const int tid = threadIdx.x;
    const int gthread = blockIdx.x * 256 + tid;
    const int nthreads = gridDim.x * 256;
    const int lane = tid & 63;
    const int wv = tid >> 6;
    const int gwave = gthread >> 6;
    const int nwaves = nthreads >> 6;
    __shared__ float lsm[4][64];

    // P0: zero cnt/total + split weights (transposed bf16 hi/lo planes)
    for (int i = gthread; i < n; i += nthreads) cnt[i] = 0;
    if (gthread == 0) *total = 0;
    for (int i = gthread; i < 128 * 256 + 256 * 64; i += nthreads) {
        if (i < 128 * 256) {
            int k = i >> 8, c = i & 255;
            float v = W1[i];
            __bf16 h = (__bf16)v, l = (__bf16)(v - (float)h);
            w1h[(size_t)c * 128 + k] = __builtin_bit_cast(unsigned short, h);
            w1l[(size_t)c * 128 + k] = __builtin_bit_cast(unsigned short, l);
        } else {
            int j = i - 128 * 256;
            int k = j >> 6, c = j & 63;
            float v = W2[j];
            __bf16 h = (__bf16)v, l = (__bf16)(v - (float)h);
            w2h[(size_t)c * 256 + k] = __builtin_bit_cast(unsigned short, h);
            w2l[(size_t)c * 256 + k] = __builtin_bit_cast(unsigned short, l);
        }
    }
    __threadfence(); grid.sync();

    // P1: degree histogram
    for (int e = gthread; e < E; e += nthreads) atomicAdd(&cnt[ei[e]], 1);
    __threadfence(); grid.sync();

    // P2: bucket allocation + dinv + pad slots
    for (int i = gthread; i < n; i += nthreads) {
        int c = cnt[i];
        int cp = (c + 7) & ~7;
        int b = atomicAdd(total, cp);
        base[i] = b;
        fill[i] = b;
        dinv[i] = rsqrtf(1.0f + (float)c);
        for (int p = b + c; p < b + cp; ++p) edge2[p] = make_int2(0, 0);
    }
    __threadfence(); grid.sync();

    // P3: scatter edges into buckets
    for (int e = gthread; e < E; e += nthreads) {
        int r = ei[e], c = ei[E + e];
        int pos = atomicAdd(&fill[r], 1);
        edge2[pos] = make_int2(c, __float_as_int(dinv[r] * dinv[c]));
    }
    __threadfence(); grid.sync();

    // P4: layer-1 aggregation (wave per node) -> split planes
    for (int w = gwave; w < n; w += nwaves)
        aggx_body(w, lane, x, base, cnt, edge2, dinv, AXh, AXl);
    __threadfence(); grid.sync();

    // P5: GEMM1 (M=n, N=256, K=128), A pre-split planes
    {
        int tiles = ((n + 31) >> 5) * 4;
        for (int gw = gwave; gw < tiles; gw += nwaves)
            gemm_tile<128, 2, 4, 1, 0, 1>(gw, lane, AXh, AXl, nullptr, w1h, w1l, b1, H1, n, 256, 1);
    }
    __threadfence(); grid.sync();

    // P6: GEMM2 (M=n, N=64, K=256), fp32 A split in-register, NT in
    {
        int tiles = (n + 15) >> 4;
        for (int gw = gwave; gw < tiles; gw += nwaves)
            gemm_tile<256, 1, 1, 0, 1, 0>(gw, lane, nullptr, nullptr, H1, w2h, w2l, nullptr, H2, n, 64, 0);
    }
    __threadfence(); grid.sync();

    // P7: layer-2 aggregation + log_softmax + vectorized 24-copy broadcast
    {
        size_t ostride = (size_t)n * 64;
        int qtot = (n + 3) >> 2;
        for (int task = blockIdx.x; task < qtot; task += gridDim.x) {
            int w = task * 4 + wv;
            float res = 0.f;
            if (w < n) res = aggh2_res(w, lane, H2, base, cnt, edge2, dinv, b2);
            lsm[wv][lane] = res;
            __syncthreads();
            int tot = copies * 64;                       // (copy, float4-slot) pairs per 4-node group
            for (int s = tid; s < tot; s += 256) {
                int c = s >> 6, sl = s & 63;
                int no = sl >> 4, f4 = sl & 15;
                if (task * 4 + no < n) {
                    f32x4 v = *(const f32x4*)&lsm[no][f4 * 4];
                    __builtin_nontemporal_store(v,
                        (f32x4*)(out + (size_t)c * ostride + (size_t)(task * 4 + no) * 64 + f4 * 4));
                }
            }
            __syncthreads();
        }
    }
}

// ================= fallback multi-kernel path (round-3 semantics, proven) =================
__global__ __launch_bounds__(256) void hist_rows(const int* __restrict__ row, int* __restrict__ cnt, int E) {
    int e = blockIdx.x * 256 + threadIdx.x;
    if (e < E) atomicAdd(&cnt[row[e]], 1);
}

__global__ __launch_bounds__(256) void alloc_buckets(const int* __restrict__ cnt,
                                                     int* __restrict__ base, int* __restrict__ fill,
                                                     float* __restrict__ dinv,
                                                     int* __restrict__ total,
                                                     int2* __restrict__ edge2, int n) {
    int i = blockIdx.x * 256 + threadIdx.x;
    if (i >= n) return;
    int c = cnt[i];
    int cp = (c + 7) & ~7;
    int b = atomicAdd(total, cp);
    base[i] = b;
    fill[i] = b;
    dinv[i] = rsqrtf(1.0f + (float)c);
    for (int p = b + c; p < b + cp; ++p) edge2[p] = make_int2(0, 0);
}

__global__ __launch_bounds__(256) void fill_buckets(const int* __restrict__ row, const int* __restrict__ col,
                                                    int* __restrict__ fill, const float* __restrict__ dinv,
                                                    int2* __restrict__ edge2, int E) {
    int e = blockIdx.x * 256 + threadIdx.x;
    if (e < E) {
        int r = row[e], c = col[e];
        int pos = atomicAdd(&fill[r], 1);
        edge2[pos] = make_int2(c, __float_as_int(dinv[r] * dinv[c]));
    }
}

__global__ __launch_bounds__(256) void split_w(const float* __restrict__ W1, const float* __restrict__ W2,
                                               unsigned short* __restrict__ w1h, unsigned short* __restrict__ w1l,
                                               unsigned short* __restrict__ w2h, unsigned short* __restrict__ w2l) {
    int i = blockIdx.x * 256 + threadIdx.x;
    if (i < 128 * 256) {
        int k = i >> 8, c = i & 255;
        float v = W1[i];
        __bf16 h = (__bf16)v, l = (__bf16)(v - (float)h);
        w1h[(size_t)c * 128 + k] = __builtin_bit_cast(unsigned short, h);
        w1l[(size_t)c * 128 + k] = __builtin_bit_cast(unsigned short, l);
    } else if (i < 128 * 256 + 256 * 64) {
        int j = i - 128 * 256;
        int k = j >> 6, c = j & 63;
        float v = W2[j];
        __bf16 h = (__bf16)v, l = (__bf16)(v - (float)h);
        w2h[(size_t)c * 256 + k] = __builtin_bit_cast(unsigned short, h);
        w2l[(size_t)c * 256 + k] = __builtin_bit_cast(unsigned short, l);
    }
}

__global__ __launch_bounds__(256) void agg_x(const float* __restrict__ x,
                                             const int* __restrict__ base, const int* __restrict__ cnt,
                                             const int2* __restrict__ edge2, const float* __restrict__ dinv,
                                             unsigned* __restrict__ AXh, unsigned* __restrict__ AXl, int n) {
    int w = (blockIdx.x * 256 + threadIdx.x) >> 6;
    int lane = threadIdx.x & 63;
    if (w >= n) return;
    aggx_body(w, lane, x, base, cnt, edge2, dinv, AXh, AXl);
}

template<int K_, int FI, int CT, int APLANES, int NTIN, int NTOUT>
__global__ __launch_bounds__(256) void gemm_direct(const unsigned* __restrict__ Ah,
                                                   const unsigned* __restrict__ Al,
                                                   const float* __restrict__ Afp,
                                                   const unsigned short* __restrict__ Bh,
                                                   const unsigned short* __restrict__ Bl,
                                                   const float* __restrict__ bias,
                                                   float* __restrict__ C,
                                                   int M, int N, int relu) {
    int gw = blockIdx.x * 4 + (threadIdx.x >> 6);
    gemm_tile<K_, FI, CT, APLANES, NTIN, NTOUT>(gw, threadIdx.x & 63, Ah, Al, Afp, Bh, Bl, bias, C, M, N, relu);
}

__global__ __launch_bounds__(256) void agg_h2_final(const float* __restrict__ H2,
                                                    const int* __restrict__ base, const int* __restrict__ cnt,
                                                    const int2* __restrict__ edge2, const float* __restrict__ dinv,
                                                    const float* __restrict__ b2,
                                                    float* __restrict__ out, int n, int copies) {
    int w = (blockIdx.x * 256 + threadIdx.x) >> 6;
    int lane = threadIdx.x & 63;
    if (w >= n) return;
    float res = aggh2_res(w, lane, H2, base, cnt, edge2, dinv, b2);
    size_t idx = (size_t)w * 64 + lane;
    size_t stride = (size_t)n * 64;
    for (int c = 0; c < copies; ++c)
        __builtin_nontemporal_store(res, out + (size_t)c * stride + idx);
}

extern "C" void kernel_launch(void* const* d_in, const int* in_sizes, int n_in,
                              void* d_out, int out_size, void* d_ws, size_t ws_size,
                              hipStream_t stream) {
    const float* x  = (const float*)d_in[0];
    const float* W1 = (const float*)d_in[1];
    const float* b1 = (const float*)d_in[2];
    const float* W2 = (const float*)d_in[3];
    const float* b2 = (const float*)d_in[4];
    const int*   ei = (const int*)d_in[5];

    const int n = in_sizes[0] / 128;              // 50000
    const int E = in_sizes[5] / 2;                // 800000
    float* out = (float*)d_out;
    const size_t stride = (size_t)n * 64;
    const int copies = (int)(out_size / stride);  // 24

    const size_t metaF  = 5 * (size_t)n + 64;
    const size_t edge2F = 2 * ((size_t)E + 8 * (size_t)n);
    const size_t h2F    = (size_t)n * 64;
    const size_t wF     = 32768 + 16384;
    const size_t needWs = (metaF + edge2F + h2F + wF) * sizeof(float);
    const bool use_ws = (d_ws != nullptr) && (ws_size >= needWs);

    float* meta  = use_ws ? (float*)d_ws : out;
    float* dinv  = meta;
    int*   cnt   = (int*)(meta + n);
    int*   base  = (int*)(meta + 2 * (size_t)n);
    int*   fill  = (int*)(meta + 3 * (size_t)n);
    int*   total = (int*)(meta + 4 * (size_t)n);
    int2*  edge2 = use_ws ? (int2*)(meta + metaF) : (int2*)(out + 1 * stride);
    float* H2    = use_ws ? (float*)(edge2 + (edge2F / 2)) : out + 8 * stride;
    unsigned short* w1h = use_ws ? (unsigned short*)(H2 + h2F)
                                 : (unsigned short*)(out + 10 * stride);
    unsigned short* w1l = w1h + 32768;
    unsigned short* w2h = w1l + 32768;
    unsigned short* w2l = w2h + 16384;

    unsigned* AXh = (unsigned*)(out + 2 * stride);
    unsigned* AXl = (unsigned*)(out + 3 * stride);
    float*    H1  = out + 4 * stride;

    // ---- preferred: single cooperative dispatch ----
    if (use_ws) {
        int bpc = 0;
        hipError_t oe = hipOccupancyMaxActiveBlocksPerMultiprocessor(&bpc, mega, 256, 0);
        if (oe == hipSuccess && bpc >= 1) {
            int grid = bpc * 256;                 // 256 CUs on gfx950; all blocks co-resident
            if (grid > 4096) grid = 4096;
            float* dinv_ = dinv; int* cnt_ = cnt; int* base_ = base; int* fill_ = fill; int* total_ = total;
            int2* edge2_ = edge2;
            unsigned short *w1h_ = w1h, *w1l_ = w1l, *w2h_ = w2h, *w2l_ = w2l;
            unsigned *AXh_ = AXh, *AXl_ = AXl;
            float *H1_ = H1, *H2_ = H2, *out_ = out;
            int n_ = n, E_ = E, copies_ = copies;
            const float *x_ = x, *W1_ = W1, *W2_ = W2, *b1_ = b1, *b2_ = b2;
            const int* ei_ = ei;
            void* kargs[] = { &x_, &W1_, &W2_, &b1_, &b2_, &ei_,
                              &dinv_, &cnt_, &base_, &fill_, &total_, &edge2_,
                              &w1h_, &w1l_, &w2h_, &w2l_,
                              &AXh_, &AXl_, &H1_, &H2_, &out_, &n_, &E_, &copies_ };
            hipError_t le = hipLaunchCooperativeKernel(mega, dim3(grid), dim3(256), kargs, 0u, stream);
            if (le == hipSuccess) return;
        }
    }

    // ---- fallback: round-3 multi-kernel sequence ----
    hipMemsetAsync(cnt, 0, (3 * (size_t)n + 64) * sizeof(int), stream);
    split_w<<<(128 * 256 + 256 * 64 + 255) / 256, 256, 0, stream>>>(W1, W2, w1h, w1l, w2h, w2l);
    hist_rows    <<<(E + 255) / 256, 256, 0, stream>>>(ei, cnt, E);
    alloc_buckets<<<(n + 255) / 256, 256, 0, stream>>>(cnt, base, fill, dinv, total, edge2, n);
    fill_buckets <<<(E + 255) / 256, 256, 0, stream>>>(ei, ei + E, fill, dinv, edge2, E);
    agg_x<<<(n + 3) / 4, 256, 0, stream>>>(x, base, cnt, edge2, dinv, AXh, AXl, n);
    {
        int rtc = (n + 31) / 32;
        gemm_direct<128, 2, 4, 1, 0, 1><<<rtc, 256, 0, stream>>>(
            AXh, AXl, nullptr, w1h, w1l, b1, H1, n, 256, 1);
    }
    {
        int rtc = (n + 15) / 16;
        gemm_direct<256, 1, 1, 0, 1, 0><<<(rtc + 3) / 4, 256, 0, stream>>>(
            nullptr, nullptr, H1, w2h, w2l, nullptr, H2, n, 64, 0);
    }
    agg_h2_final<<<(n + 3) / 4, 256, 0, stream>>>(H2, base, cnt, edge2, dinv, b2, out, n, copies);
}